// Round 7
// baseline (221.579 us; speedup 1.0000x reference)
//
#include <hip/hip_runtime.h>
#include <hip/hip_bf16.h>

#define BDIM 2
#define DDIM 128
#define HDIM 128
#define WDIM 128
#define CI 64
#define CO 64
#define NTAPS 27
#define GRID_CELLS (BDIM * DDIM * HDIM * WDIM)  // 4,194,304
#define NCBLK (GRID_CELLS / 256)                // 16384

typedef __attribute__((ext_vector_type(8))) short short8;
typedef __attribute__((ext_vector_type(4))) float floatx4;

// ws layout:
//   [0, 16 MB)   grid: orig idx after scatter, RANK after emit (in-place)
//   +16 MB       wt8 B-fragments (256 KB)
//   +16.25 MB    bcnt int[16384]
//   +16.3125 MB  order int[N]  (rank -> orig idx)
//   +~17.3 MB    fs: bf16 feats in sorted-rank order, N*128 B (optional)
#define WT_OFF   ((size_t)16 << 20)
#define BCNT_OFF (WT_OFF + ((size_t)256 << 10))
#define ORD_OFF  (BCNT_OFF + ((size_t)64 << 10))
#define FS_OFF   (ORD_OFF + ((size_t)1 << 20))

__device__ __forceinline__ unsigned short f2bf(float f) {
    unsigned int u = __float_as_uint(f);
    return (unsigned short)((u + 0x7FFFu + ((u >> 16) & 1u)) >> 16);  // RNE
}

__global__ __launch_bounds__(256) void scatter_kernel(
    const int* __restrict__ coords, int* __restrict__ grid, int n) {
    int i = blockIdx.x * blockDim.x + threadIdx.x;
    if (i >= n) return;
    int4 c = ((const int4*)coords)[i];  // b, z, y, x
    grid[((c.x * DDIM + c.y) * HDIM + c.z) * WDIM + c.w] = i;
}

// Pack weight (CO,3,3,3,CI) into MFMA B-fragment layout, bf16:
// wt8[t*512 + (s*4+ot)*64 + l][j] = W[ot*16+(l&15)][t][s*32+(l>>4)*8+j]
__global__ __launch_bounds__(256) void wfrag_kernel(
    const float* __restrict__ weight, short8* __restrict__ wt8) {
    int idx = blockIdx.x * blockDim.x + threadIdx.x;
    if (idx >= NTAPS * 2 * 4 * 64) return;
    int l = idx & 63, ot = (idx >> 6) & 3, s = (idx >> 8) & 1, t = idx >> 9;
    int o = ot * 16 + (l & 15);
    int k0 = s * 32 + ((l >> 4) << 3);
    const float* src = weight + ((size_t)o * NTAPS + t) * CI + k0;
    short8 v;
#pragma unroll
    for (int j = 0; j < 8; ++j) v[j] = (short)f2bf(src[j]);
    wt8[idx] = v;
}

// ---- grid stream-compaction (deterministic spatial sort) ----
__global__ __launch_bounds__(256) void count_kernel(
    const int* __restrict__ grid, int* __restrict__ bcnt) {
    int i = blockIdx.x * 256 + threadIdx.x;
    unsigned long long b = __ballot(grid[i] >= 0);
    __shared__ int wc[4];
    if ((threadIdx.x & 63) == 0) wc[threadIdx.x >> 6] = __popcll(b);
    __syncthreads();
    if (threadIdx.x == 0) bcnt[blockIdx.x] = wc[0] + wc[1] + wc[2] + wc[3];
}

__global__ __launch_bounds__(1024) void scan_kernel(int* __restrict__ bcnt) {
    __shared__ int part[1024];
    int tid = threadIdx.x;
    int v[16], s = 0;
#pragma unroll
    for (int k = 0; k < 16; ++k) { v[k] = bcnt[tid * 16 + k]; s += v[k]; }
    part[tid] = s;
    __syncthreads();
    for (int off = 1; off < 1024; off <<= 1) {
        int t = (tid >= off) ? part[tid - off] : 0;
        __syncthreads();
        part[tid] += t;
        __syncthreads();
    }
    int ex = tid ? part[tid - 1] : 0;
#pragma unroll
    for (int k = 0; k < 16; ++k) { int nv = ex; ex += v[k]; bcnt[tid * 16 + k] = nv; }
}

// Emits order[rank]=orig and rewrites grid cell to its RANK (in place).
__global__ __launch_bounds__(256) void emit_kernel(
    const int* __restrict__ boff, int* __restrict__ grid,
    int* __restrict__ order) {
    int i = blockIdx.x * 256 + threadIdx.x;
    int v = grid[i];
    int lane = threadIdx.x & 63, w = threadIdx.x >> 6;
    unsigned long long b = __ballot(v >= 0);
    __shared__ int wc[4];
    if (lane == 0) wc[w] = __popcll(b);
    __syncthreads();
    int woff = 0;
    for (int k = 0; k < w; ++k) woff += wc[k];
    int rank = -1;
    if (v >= 0) {
        rank = boff[blockIdx.x] + woff + __popcll(b & ((1ull << lane) - 1ull));
        order[rank] = v;
    }
    grid[i] = rank;
}

// fs[rank] = bf16(feats[order[rank]]), 128 B rows; one half-wave per row.
__global__ __launch_bounds__(256) void fperm_kernel(
    const float* __restrict__ feats, const int* __restrict__ order,
    unsigned int* __restrict__ fso, int n) {
    int row = blockIdx.x * 8 + (threadIdx.x >> 5);
    if (row >= n) return;
    int sub = threadIdx.x & 31;
    int p = order[row];
    float2 v = ((const float2*)(feats + (size_t)p * CI))[sub];
    __hip_bfloat162 b = __float22bfloat162_rn(float2{v.x, v.y});
    fso[(size_t)row * 32 + sub] = *(unsigned int*)&b;
}

// ---- fused conv: 512-thr block = 8 waves x 16 points = 128 points ----
// Weights staged in 4 tap-groups (7,7,7,6 x 8 KB = 56 KB LDS max); only 2
// barriers per group (8/block) — taps inside a group run barrier-free.
template <bool USE_FS>
__global__ __launch_bounds__(512, 4) void conv_kernel(
    const float* __restrict__ feats, const short* __restrict__ fs,
    const short8* __restrict__ wt8, const float* __restrict__ bias,
    const int* __restrict__ coords, const int* __restrict__ rgrid,
    const int* __restrict__ order, float* __restrict__ out, int n) {
    __shared__ short8 bs[7 * 512];  // 56 KB
    int tid = threadIdx.x;
    int w = tid >> 6, l = tid & 63, quad = l >> 4, m = l & 15;
    int jrow = blockIdx.x * 128 + w * 16 + m;
    int j = jrow < n ? jrow : n - 1;
    int p = order[j];
    int4 c = ((const int4*)coords)[p];

    // Probe phase: probe i covers tap t = 4*i + quad for row m. Value = RANK.
    int pr[7];
#pragma unroll
    for (int i = 0; i < 7; ++i) {
        int t = 4 * i + quad;
        int v = -1;
        if (t < NTAPS) {
            int dz = t / 9 - 1, rem = t % 9;
            int dy = rem / 3 - 1, dx = rem % 3 - 1;
            int nz = c.y + dz, ny = c.z + dy, nx = c.w + dx;
            if (nz >= 0 && nz < DDIM && ny >= 0 && ny < HDIM &&
                nx >= 0 && nx < WDIM)
                v = rgrid[((c.x * DDIM + nz) * HDIM + ny) * WDIM + nx];
        }
        pr[i] = v;
    }

    floatx4 acc0 = {0.f, 0.f, 0.f, 0.f}, acc1 = acc0, acc2 = acc0, acc3 = acc0;

#define STAGE_GRP(T0, SZ)                                            \
    __syncthreads();                                                 \
    for (int i = tid; i < (SZ) * 512; i += 512)                      \
        bs[i] = wt8[(T0) * 512 + i];                                 \
    __syncthreads();

#define TAP(T, T0)                                                                 \
    {                                                                              \
        int rk = __shfl(pr[(T) >> 2], (((T) & 3) << 4) | m);                       \
        if (__ballot(rk >= 0) != 0ull) {                                           \
            short8 a0 = {0, 0, 0, 0, 0, 0, 0, 0};                                  \
            short8 a1 = {0, 0, 0, 0, 0, 0, 0, 0};                                  \
            if (rk >= 0) {                                                         \
                if (USE_FS) {                                                      \
                    const short8* ar = (const short8*)(fs + (size_t)rk * CI);      \
                    a0 = ar[quad];                                                 \
                    a1 = ar[quad + 4];                                             \
                } else {                                                           \
                    int op = order[rk];                                            \
                    const float4* ar =                                             \
                        (const float4*)(feats + (size_t)op * CI + quad * 8);       \
                    float4 x0 = ar[0], x1 = ar[1], x2 = ar[8], x3 = ar[9];         \
                    union { short8 sv; __hip_bfloat162 hv[4]; } u0, u1;            \
                    u0.hv[0] = __float22bfloat162_rn(float2{x0.x, x0.y});          \
                    u0.hv[1] = __float22bfloat162_rn(float2{x0.z, x0.w});          \
                    u0.hv[2] = __float22bfloat162_rn(float2{x1.x, x1.y});          \
                    u0.hv[3] = __float22bfloat162_rn(float2{x1.z, x1.w});          \
                    u1.hv[0] = __float22bfloat162_rn(float2{x2.x, x2.y});          \
                    u1.hv[1] = __float22bfloat162_rn(float2{x2.z, x2.w});          \
                    u1.hv[2] = __float22bfloat162_rn(float2{x3.x, x3.y});          \
                    u1.hv[3] = __float22bfloat162_rn(float2{x3.z, x3.w});          \
                    a0 = u0.sv;                                                    \
                    a1 = u1.sv;                                                    \
                }                                                                  \
            }                                                                      \
            const short8* wb = bs + ((T) - (T0)) * 512 + l;                        \
            acc0 = __builtin_amdgcn_mfma_f32_16x16x32_bf16(a0, wb[0 * 64], acc0, 0, 0, 0); \
            acc1 = __builtin_amdgcn_mfma_f32_16x16x32_bf16(a0, wb[1 * 64], acc1, 0, 0, 0); \
            acc2 = __builtin_amdgcn_mfma_f32_16x16x32_bf16(a0, wb[2 * 64], acc2, 0, 0, 0); \
            acc3 = __builtin_amdgcn_mfma_f32_16x16x32_bf16(a0, wb[3 * 64], acc3, 0, 0, 0); \
            acc0 = __builtin_amdgcn_mfma_f32_16x16x32_bf16(a1, wb[4 * 64], acc0, 0, 0, 0); \
            acc1 = __builtin_amdgcn_mfma_f32_16x16x32_bf16(a1, wb[5 * 64], acc1, 0, 0, 0); \
            acc2 = __builtin_amdgcn_mfma_f32_16x16x32_bf16(a1, wb[6 * 64], acc2, 0, 0, 0); \
            acc3 = __builtin_amdgcn_mfma_f32_16x16x32_bf16(a1, wb[7 * 64], acc3, 0, 0, 0); \
        }                                                                          \
    }

    STAGE_GRP(0, 7)
    TAP(0, 0) TAP(1, 0) TAP(2, 0) TAP(3, 0) TAP(4, 0) TAP(5, 0) TAP(6, 0)
    STAGE_GRP(7, 7)
    TAP(7, 7) TAP(8, 7) TAP(9, 7) TAP(10, 7) TAP(11, 7) TAP(12, 7) TAP(13, 7)
    STAGE_GRP(14, 7)
    TAP(14, 14) TAP(15, 14) TAP(16, 14) TAP(17, 14) TAP(18, 14) TAP(19, 14) TAP(20, 14)
    STAGE_GRP(21, 6)
    TAP(21, 21) TAP(22, 21) TAP(23, 21) TAP(24, 21) TAP(25, 21) TAP(26, 21)

#undef STAGE_GRP
#undef TAP

    // C layout: channel col = m, point row = quad*4 + reg.
    float b0 = bias[m], b1 = bias[m + 16], b2 = bias[m + 32], b3 = bias[m + 48];
#pragma unroll
    for (int r = 0; r < 4; ++r) {
        int row = quad * 4 + r;
        int jr = blockIdx.x * 128 + w * 16 + row;
        int prow = __shfl(p, row);  // lane `row` (quad 0) holds row's point idx
        if (jr < n) {
            float* orow = out + (size_t)prow * CO;
            orow[m]      = acc0[r] + b0;
            orow[m + 16] = acc1[r] + b1;
            orow[m + 32] = acc2[r] + b2;
            orow[m + 48] = acc3[r] + b3;
        }
    }
}

extern "C" void kernel_launch(void* const* d_in, const int* in_sizes, int n_in,
                              void* d_out, int out_size, void* d_ws, size_t ws_size,
                              hipStream_t stream) {
    const float* feats  = (const float*)d_in[0];
    const float* weight = (const float*)d_in[1];
    const float* bias   = (const float*)d_in[2];
    const int*   coords = (const int*)d_in[3];
    float* out = (float*)d_out;
    int n = in_sizes[3] / 4;

    int*    grid  = (int*)d_ws;
    short8* wt8   = (short8*)((char*)d_ws + WT_OFF);
    int*    bcnt  = (int*)((char*)d_ws + BCNT_OFF);
    int*    order = (int*)((char*)d_ws + ORD_OFF);
    short*  fs    = (short*)((char*)d_ws + FS_OFF);

    // ws_size is constant across calls -> same work every call.
    bool use_fs = ws_size >= FS_OFF + (size_t)n * CI * sizeof(short);

    (void)hipMemsetAsync(grid, 0xFF, (size_t)GRID_CELLS * sizeof(int), stream);
    scatter_kernel<<<(n + 255) / 256, 256, 0, stream>>>(coords, grid, n);
    wfrag_kernel<<<(NTAPS * 2 * 4 * 64 + 255) / 256, 256, 0, stream>>>(weight, wt8);
    count_kernel<<<NCBLK, 256, 0, stream>>>(grid, bcnt);
    scan_kernel<<<1, 1024, 0, stream>>>(bcnt);
    emit_kernel<<<NCBLK, 256, 0, stream>>>(bcnt, grid, order);
    int cblocks = (n + 127) / 128;
    if (use_fs) {
        fperm_kernel<<<(n + 7) / 8, 256, 0, stream>>>(feats, order, (unsigned int*)fs, n);
        conv_kernel<true><<<cblocks, 512, 0, stream>>>(
            feats, fs, wt8, bias, coords, grid, order, out, n);
    } else {
        conv_kernel<false><<<cblocks, 512, 0, stream>>>(
            feats, fs, wt8, bias, coords, grid, order, out, n);
    }
}